// Round 4
// baseline (342.952 us; speedup 1.0000x reference)
//
#include <hip/hip_runtime.h>

typedef __attribute__((ext_vector_type(4))) float          f32x4;
typedef __attribute__((ext_vector_type(8))) __bf16         bf16x8;
typedef __attribute__((ext_vector_type(8))) unsigned short u16x8;

#define B_  1024
#define D_  2048
#define H_  2048
#define K_  4096   /* D + H  */
#define N_  8192   /* 4 * H  */

// ---------- helpers ----------
__device__ __forceinline__ unsigned short f2bf_rne(float f) {
  unsigned u = __builtin_bit_cast(unsigned, f);
  u += 0x7fffu + ((u >> 16) & 1u);           // round-to-nearest-even
  return (unsigned short)(u >> 16);
}

__device__ __forceinline__ float sigf(float x) {
  return 1.f / (1.f + __expf(-x));
}
__device__ __forceinline__ float tanhf_(float x) {
  float ax = fabsf(x);
  float t  = __expf(-2.f * ax);              // in (0,1], no overflow
  float r  = (1.f - t) / (1.f + t);
  return (x < 0.f) ? -r : r;
}

typedef const __attribute__((address_space(1))) unsigned int* gptr_t;
typedef __attribute__((address_space(3))) unsigned int*       lptr_t;
__device__ __forceinline__ void gl_lds16(const void* g, void* l) {
  __builtin_amdgcn_global_load_lds((gptr_t)g, (lptr_t)l, 16, 0, 0);
}

// ---------- kernel 1: convert [x | h] -> bf16 merged (1024 x 4096) ----------
__global__ __launch_bounds__(256) void k_convert_merged(
    const float* __restrict__ x, const float* __restrict__ h,
    unsigned short* __restrict__ merged) {
  int tid = blockIdx.x * 256 + threadIdx.x;   // 0 .. 524287
  int e0  = tid * 8;                          // element offset in merged
  int b   = e0 >> 12;                         // / 4096
  int col = e0 & 4095;
  const float* src = (col < D_) ? (x + (size_t)b * D_ + col)
                                : (h + (size_t)b * H_ + (col - D_));
  f32x4 v0 = *(const f32x4*)src;
  f32x4 v1 = *(const f32x4*)(src + 4);
  u16x8 o;
  o[0] = f2bf_rne(v0[0]); o[1] = f2bf_rne(v0[1]);
  o[2] = f2bf_rne(v0[2]); o[3] = f2bf_rne(v0[3]);
  o[4] = f2bf_rne(v1[0]); o[5] = f2bf_rne(v1[1]);
  o[6] = f2bf_rne(v1[2]); o[7] = f2bf_rne(v1[3]);
  *(u16x8*)(merged + e0) = o;
}

// ---------- kernel 2: W (4096x8192 f32, KxN) -> Wt' (8192x4096 bf16) --------
// GATE-INTERLEAVED: Wt' row n' = 4*j + g  holds  W[:, g*2048 + j].
// Permutation applied on the read/store side only: block bx covers source
// cols [g*2048 + jb*64, +64) with g = bx&3, jb = bx>>2; output rows 4*j+g.
// LDS: 64x64 f32 tile, XOR-swizzle byte ^= ((k>>3)&7)<<4 on BOTH phases.
__global__ __launch_bounds__(256) void k_transpose_w(
    const float* __restrict__ W, unsigned short* __restrict__ Wt) {
  __shared__ float lt[64 * 64];
  char* lbase = (char*)lt;
  const int t   = threadIdx.x;
  const int g   = blockIdx.x & 3;
  const int jb  = blockIdx.x >> 2;            // 0..31
  const int n0s = g * 2048 + jb * 64;         // source col base in W
  const int k0  = blockIdx.y * 64;            // 4096/64 = 64
#pragma unroll
  for (int i = 0; i < 4; ++i) {
    int kk = (t >> 4) + i * 16;               // 0..63
    int nn = (t & 15) * 4;                    // 0..60 (source-col offset)
    f32x4 v = *(const f32x4*)&W[(size_t)(k0 + kk) * N_ + n0s + nn];
    int by = (kk * 256 + nn * 4) ^ (((kk >> 3) & 7) << 4);
    *(f32x4*)(lbase + by) = v;
  }
  __syncthreads();
#pragma unroll
  for (int i = 0; i < 2; ++i) {
    int jl = (t >> 3) + i * 32;               // 0..63 (j within tile)
    int kc = (t & 7) * 8;                     // 0..56, k>>3 == t&7 for all jj
    u16x8 o;
#pragma unroll
    for (int jj = 0; jj < 8; ++jj) {
      int k  = kc + jj;
      int by = (k * 256 + jl * 4) ^ (((k >> 3) & 7) << 4);
      o[jj] = f2bf_rne(*(const float*)(lbase + by));
    }
    int nrow = 4 * (jb * 64 + jl) + g;        // gate-interleaved output row
    *(u16x8*)&Wt[(size_t)nrow * K_ + k0 + kc] = o;
  }
}

// ---------- kernel 3: fused GEMM + LSTM gates ------------------------------
// C' = merged(1024x4096 bf16) @ Wt'^T; col' = 4*j+gate, so the quad of lanes
// {4q..4q+3} holds (f,i,g,o) of output j. 3x shfl_xor gathers them; quad-lane
// 0 computes h_new and stores. GEMM body identical to rounds 2-3 (m97 128^2).
#define TM 128
#define TN 128
#define TK 64

__global__ __launch_bounds__(256) void k_gemm(
    const unsigned short* __restrict__ A,   // M x K bf16 row-major
    const unsigned short* __restrict__ Bt,  // N x K bf16 row-major (permuted)
    const float* __restrict__ c,            // B x H f32
    float* __restrict__ out) {              // B x H f32 (h_new)
  __shared__ unsigned short As[TM * TK];    // [128][64], row stride 128 B
  __shared__ unsigned short Bs[TN * TK];
  const int t    = threadIdx.x;
  const int bx   = blockIdx.x;              // N tile: 0..63
  const int by   = blockIdx.y;              // M tile: 0..7
  const int wid  = t >> 6;
  const int lane = t & 63;
  const int wr   = wid >> 1, wc = wid & 1;  // 2x2 waves, 64x64 each
  const int ln15 = lane & 15, kq = lane >> 4;

  const int srow  = t >> 3;                 // 0..31 per sweep
  const int scolb = (t & 7) * 16;           // byte col within 128-B row

  const char* gA = (const char*)A + (size_t)(by * TM + srow) * (K_ * 2) + scolb;
  const char* gB = (const char*)Bt + (size_t)(bx * TN + srow) * (K_ * 2) + scolb;
  char* lA = (char*)As + srow * (TK * 2) + scolb;
  char* lB = (char*)Bs + srow * (TK * 2) + scolb;

  f32x4 acc[4][4] = {};

  for (int kt = 0; kt < K_ / TK; ++kt) {
    const int gofs = kt * (TK * 2);         // byte offset along K
#pragma unroll
    for (int i = 0; i < 4; ++i) {           // 32 rows per sweep
      gl_lds16(gA + (size_t)(i * 32) * (K_ * 2) + gofs, lA + i * 32 * (TK * 2));
      gl_lds16(gB + (size_t)(i * 32) * (K_ * 2) + gofs, lB + i * 32 * (TK * 2));
    }
    __syncthreads();
#pragma unroll
    for (int ks = 0; ks < 2; ++ks) {        // two K=32 sub-steps
      bf16x8 a[4], b[4];
#pragma unroll
      for (int mi = 0; mi < 4; ++mi)
        a[mi] = *(const bf16x8*)((const char*)As +
                 (wr * 64 + mi * 16 + ln15) * (TK * 2) + ks * 64 + kq * 16);
#pragma unroll
      for (int ni = 0; ni < 4; ++ni)
        b[ni] = *(const bf16x8*)((const char*)Bs +
                 (wc * 64 + ni * 16 + ln15) * (TK * 2) + ks * 64 + kq * 16);
#pragma unroll
      for (int mi = 0; mi < 4; ++mi)
#pragma unroll
        for (int ni = 0; ni < 4; ++ni)
          acc[mi][ni] = __builtin_amdgcn_mfma_f32_16x16x32_bf16(
              a[mi], b[ni], acc[mi][ni], 0, 0, 0);
    }
    __syncthreads();
  }

  // fused epilogue. C/D layout: col = lane&15, row = (lane>>4)*4 + reg.
  // col' = bx*128 + wc*64 + ni*16 + ln15 ; gate = ln15&3 ; j = col'>>2.
  const int crow0 = by * TM + wr * 64 + kq * 4;
  const int s     = ln15 & 3;               // gate of this lane
  const int q     = ln15 >> 2;
  const int jbase = bx * 32 + wc * 16 + q;  // + ni*4
#pragma unroll
  for (int mi = 0; mi < 4; ++mi)
#pragma unroll
    for (int ni = 0; ni < 4; ++ni)
#pragma unroll
      for (int r = 0; r < 4; ++r) {
        float v  = acc[mi][ni][r];
        float v1 = __shfl_xor(v, 1);
        float v2 = __shfl_xor(v, 2);
        float v3 = __shfl_xor(v, 3);
        if (s == 0) {                       // lane holds f; v1=i, v2=g, v3=o
          int row = crow0 + mi * 16 + r;
          int j   = jbase + ni * 4;
          float cv = c[(size_t)row * H_ + j];
          float cn = cv * sigf(v) + sigf(v1) * tanhf_(v2);
          out[(size_t)row * H_ + j] = sigf(v3) * tanhf_(cn);
        }
      }
}

// ---------- launch ----------
extern "C" void kernel_launch(void* const* d_in, const int* in_sizes, int n_in,
                              void* d_out, int out_size, void* d_ws, size_t ws_size,
                              hipStream_t stream) {
  (void)in_sizes; (void)n_in; (void)out_size; (void)ws_size;
  const float* x = (const float*)d_in[0];
  const float* h = (const float*)d_in[1];
  const float* c = (const float*)d_in[2];
  const float* W = (const float*)d_in[3];
  float* out = (float*)d_out;

  char* ws = (char*)d_ws;
  unsigned short* merged = (unsigned short*)ws;                              // 8 MB
  unsigned short* Wt     = (unsigned short*)(ws + (size_t)8  * 1024 * 1024); // 64 MB

  k_convert_merged<<<2048, 256, 0, stream>>>(x, h, merged);
  k_transpose_w<<<dim3(128, 64), 256, 0, stream>>>(W, Wt);
  k_gemm<<<dim3(N_ / TN, B_ / TM), 256, 0, stream>>>(merged, Wt, c, out);
}

// Round 5
// 319.833 us; speedup vs baseline: 1.0723x; 1.0723x over previous
//
#include <hip/hip_runtime.h>

typedef __attribute__((ext_vector_type(4))) float          f32x4;
typedef __attribute__((ext_vector_type(8))) __bf16         bf16x8;
typedef __attribute__((ext_vector_type(8))) unsigned short u16x8;

#define B_  1024
#define D_  2048
#define H_  2048
#define K_  4096   /* D + H  */
#define N_  8192   /* 4 * H  */

// ---------- helpers ----------
__device__ __forceinline__ unsigned short f2bf_rne(float f) {
  unsigned u = __builtin_bit_cast(unsigned, f);
  u += 0x7fffu + ((u >> 16) & 1u);           // round-to-nearest-even
  return (unsigned short)(u >> 16);
}

__device__ __forceinline__ float sigf(float x) {
  return 1.f / (1.f + __expf(-x));
}
__device__ __forceinline__ float tanhf_(float x) {
  float ax = fabsf(x);
  float t  = __expf(-2.f * ax);              // in (0,1], no overflow
  float r  = (1.f - t) / (1.f + t);
  return (x < 0.f) ? -r : r;
}

typedef const __attribute__((address_space(1))) unsigned int* gptr_t;
typedef __attribute__((address_space(3))) unsigned int*       lptr_t;
__device__ __forceinline__ void gl_lds16(const void* g, void* l) {
  __builtin_amdgcn_global_load_lds((gptr_t)g, (lptr_t)l, 16, 0, 0);
}

// ---------- kernel 1: convert [x | h] -> bf16 merged (1024 x 4096) ----------
__global__ __launch_bounds__(256) void k_convert_merged(
    const float* __restrict__ x, const float* __restrict__ h,
    unsigned short* __restrict__ merged) {
  int tid = blockIdx.x * 256 + threadIdx.x;   // 0 .. 524287
  int e0  = tid * 8;                          // element offset in merged
  int b   = e0 >> 12;                         // / 4096
  int col = e0 & 4095;
  const float* src = (col < D_) ? (x + (size_t)b * D_ + col)
                                : (h + (size_t)b * H_ + (col - D_));
  f32x4 v0 = *(const f32x4*)src;
  f32x4 v1 = *(const f32x4*)(src + 4);
  u16x8 o;
  o[0] = f2bf_rne(v0[0]); o[1] = f2bf_rne(v0[1]);
  o[2] = f2bf_rne(v0[2]); o[3] = f2bf_rne(v0[3]);
  o[4] = f2bf_rne(v1[0]); o[5] = f2bf_rne(v1[1]);
  o[6] = f2bf_rne(v1[2]); o[7] = f2bf_rne(v1[3]);
  *(u16x8*)(merged + e0) = o;
}

// ---------- kernel 2: W (4096x8192 f32, KxN) -> Wt'' (8192x4096 bf16) -------
// GATE-BLOCK-16 layout: Wt'' row n'' = (j>>4)*64 + gate*16 + (j&15) holds
// W[:, gate*2048 + j].  In the GEMM, a wave's ni=0..3 fragments then carry
// the four gates of the SAME 16 j's -> shuffle-free fused epilogue.
// LDS: 64x64 f32 tile, XOR-swizzle byte ^= ((k>>3)&7)<<4 on BOTH phases.
__global__ __launch_bounds__(256) void k_transpose_w(
    const float* __restrict__ W, unsigned short* __restrict__ Wt) {
  __shared__ float lt[64 * 64];
  char* lbase = (char*)lt;
  const int t   = threadIdx.x;
  const int g   = blockIdx.x & 3;
  const int jb  = blockIdx.x >> 2;            // 0..31
  const int n0s = g * 2048 + jb * 64;         // source col base in W
  const int k0  = blockIdx.y * 64;            // 4096/64 = 64
#pragma unroll
  for (int i = 0; i < 4; ++i) {
    int kk = (t >> 4) + i * 16;               // 0..63
    int nn = (t & 15) * 4;                    // 0..60 (source-col offset)
    f32x4 v = *(const f32x4*)&W[(size_t)(k0 + kk) * N_ + n0s + nn];
    int by = (kk * 256 + nn * 4) ^ (((kk >> 3) & 7) << 4);
    *(f32x4*)(lbase + by) = v;
  }
  __syncthreads();
#pragma unroll
  for (int i = 0; i < 2; ++i) {
    int jl = (t >> 3) + i * 32;               // 0..63 (j within tile)
    int kc = (t & 7) * 8;                     // 0..56, k>>3 == t&7 for all jj
    u16x8 o;
#pragma unroll
    for (int jj = 0; jj < 8; ++jj) {
      int k  = kc + jj;
      int by = (k * 256 + jl * 4) ^ (((k >> 3) & 7) << 4);
      o[jj] = f2bf_rne(*(const float*)(lbase + by));
    }
    int j    = jb * 64 + jl;                  // j within this gate (0..2047)
    int nrow = ((j >> 4) * 64) + g * 16 + (j & 15);
    *(u16x8*)&Wt[(size_t)nrow * K_ + k0 + kc] = o;
  }
}

// ---------- kernel 3: fused GEMM + LSTM gates ------------------------------
// 128x128 tile, TK=64, 512 threads = 8 waves as 4(M) x 2(N); per-wave 32x64
// sub-tile, acc[2][4] with ni == gate. 2-barrier m97-style loop, linear LDS,
// global_load_lds width-16 staging (dest = As + t*16: wave base + lane*16).
#define TM 128
#define TN 128
#define TK 64

__global__ __launch_bounds__(512, 4) void k_gemm(
    const unsigned short* __restrict__ A,   // M x K bf16 row-major
    const unsigned short* __restrict__ Bt,  // N x K bf16 row-major (gate-16)
    const float* __restrict__ c,            // B x H f32
    float* __restrict__ out) {              // B x H f32 (h_new)
  __shared__ unsigned short As[TM * TK];    // [128][64], row stride 128 B
  __shared__ unsigned short Bs[TN * TK];
  const int t    = threadIdx.x;             // 0..511
  const int bx   = blockIdx.x;              // N tile: 0..63
  const int by   = blockIdx.y;              // M tile: 0..7
  const int w    = t >> 6;                  // wave 0..7
  const int lane = t & 63;
  const int wr   = w >> 1, wc = w & 1;      // 4(M) x 2(N)
  const int ln15 = lane & 15, kq = lane >> 4;

  // staging: wave w covers LDS rows [w*8, w*8+8) per sweep; lane>>3 = row,
  // lane&7 = 16B chunk. LDS dest As + t*16 is wave-uniform base + lane*16.
  const int srow  = w * 8 + (lane >> 3);    // 0..63 (sweep 1 adds 64)
  const int chunk = (lane & 7) * 16;        // byte col within 128-B row

  const char* gA = (const char*)A  + (size_t)(by * TM + srow) * (K_ * 2) + chunk;
  const char* gB = (const char*)Bt + (size_t)(bx * TN + srow) * (K_ * 2) + chunk;
  char* lA = (char*)As + t * 16;
  char* lB = (char*)Bs + t * 16;
  const size_t half = (size_t)64 * (K_ * 2); // 64 rows ahead, sweep 2

  f32x4 acc[2][4] = {};

  for (int kt = 0; kt < K_ / TK; ++kt) {
    const int gofs = kt * (TK * 2);         // byte offset along K
    gl_lds16(gA + gofs,        lA);
    gl_lds16(gA + half + gofs, lA + 8192);
    gl_lds16(gB + gofs,        lB);
    gl_lds16(gB + half + gofs, lB + 8192);
    __syncthreads();
#pragma unroll
    for (int ks = 0; ks < 2; ++ks) {        // two K=32 sub-steps
      bf16x8 a[2], b[4];
#pragma unroll
      for (int mi = 0; mi < 2; ++mi)
        a[mi] = *(const bf16x8*)((const char*)As +
                 (wr * 32 + mi * 16 + ln15) * (TK * 2) + ks * 64 + kq * 16);
#pragma unroll
      for (int ni = 0; ni < 4; ++ni)
        b[ni] = *(const bf16x8*)((const char*)Bs +
                 (wc * 64 + ni * 16 + ln15) * (TK * 2) + ks * 64 + kq * 16);
#pragma unroll
      for (int mi = 0; mi < 2; ++mi)
#pragma unroll
        for (int ni = 0; ni < 4; ++ni)
          acc[mi][ni] = __builtin_amdgcn_mfma_f32_16x16x32_bf16(
              a[mi], b[ni], acc[mi][ni], 0, 0, 0);
    }
    __syncthreads();
  }

  // fused epilogue, shuffle-free: C/D layout col = lane&15, row = kq*4 + reg.
  // Wave's ni = gate; its 16 cols (ln15) = j = (bx*2+wc)*16 + ln15.
  const int row0 = by * TM + wr * 32 + kq * 4;
  const int j    = (bx * 2 + wc) * 16 + ln15;
#pragma unroll
  for (int mi = 0; mi < 2; ++mi)
#pragma unroll
    for (int r = 0; r < 4; ++r) {
      int row   = row0 + mi * 16 + r;
      float fg  = acc[mi][0][r];
      float ig  = acc[mi][1][r];
      float gg  = acc[mi][2][r];
      float og  = acc[mi][3][r];
      float cv  = c[(size_t)row * H_ + j];
      float cn  = cv * sigf(fg) + sigf(ig) * tanhf_(gg);
      out[(size_t)row * H_ + j] = sigf(og) * tanhf_(cn);
    }
}

// ---------- launch ----------
extern "C" void kernel_launch(void* const* d_in, const int* in_sizes, int n_in,
                              void* d_out, int out_size, void* d_ws, size_t ws_size,
                              hipStream_t stream) {
  (void)in_sizes; (void)n_in; (void)out_size; (void)ws_size;
  const float* x = (const float*)d_in[0];
  const float* h = (const float*)d_in[1];
  const float* c = (const float*)d_in[2];
  const float* W = (const float*)d_in[3];
  float* out = (float*)d_out;

  char* ws = (char*)d_ws;
  unsigned short* merged = (unsigned short*)ws;                              // 8 MB
  unsigned short* Wt     = (unsigned short*)(ws + (size_t)8  * 1024 * 1024); // 64 MB

  k_convert_merged<<<2048, 256, 0, stream>>>(x, h, merged);
  k_transpose_w<<<dim3(128, 64), 256, 0, stream>>>(W, Wt);
  k_gemm<<<dim3(N_ / TN, B_ / TM), 512, 0, stream>>>(merged, Wt, c, out);
}

// Round 6
// 283.705 us; speedup vs baseline: 1.2088x; 1.1273x over previous
//
#include <hip/hip_runtime.h>

typedef __attribute__((ext_vector_type(4))) float          f32x4;
typedef __attribute__((ext_vector_type(8))) __bf16         bf16x8;
typedef __attribute__((ext_vector_type(8))) unsigned short u16x8;

#define B_  1024
#define D_  2048
#define H_  2048
#define K_  4096   /* D + H  */
#define N_  8192   /* 4 * H  */

// ---------- helpers ----------
__device__ __forceinline__ unsigned short f2bf_rne(float f) {
  unsigned u = __builtin_bit_cast(unsigned, f);
  u += 0x7fffu + ((u >> 16) & 1u);           // round-to-nearest-even
  return (unsigned short)(u >> 16);
}

__device__ __forceinline__ float sigf(float x) {
  return 1.f / (1.f + __expf(-x));
}
__device__ __forceinline__ float tanhf_(float x) {
  float ax = fabsf(x);
  float t  = __expf(-2.f * ax);              // in (0,1], no overflow
  float r  = (1.f - t) / (1.f + t);
  return (x < 0.f) ? -r : r;
}

typedef const __attribute__((address_space(1))) unsigned int* gptr_t;
typedef __attribute__((address_space(3))) unsigned int*       lptr_t;
__device__ __forceinline__ void gl_lds16(const void* g, void* l) {
  __builtin_amdgcn_global_load_lds((gptr_t)g, (lptr_t)l, 16, 0, 0);
}

// ---------- kernel 1: convert [x | h] -> bf16 merged (1024 x 4096) ----------
__global__ __launch_bounds__(256) void k_convert_merged(
    const float* __restrict__ x, const float* __restrict__ h,
    unsigned short* __restrict__ merged) {
  int tid = blockIdx.x * 256 + threadIdx.x;   // 0 .. 524287
  int e0  = tid * 8;                          // element offset in merged
  int b   = e0 >> 12;                         // / 4096
  int col = e0 & 4095;
  const float* src = (col < D_) ? (x + (size_t)b * D_ + col)
                                : (h + (size_t)b * H_ + (col - D_));
  f32x4 v0 = *(const f32x4*)src;
  f32x4 v1 = *(const f32x4*)(src + 4);
  u16x8 o;
  o[0] = f2bf_rne(v0[0]); o[1] = f2bf_rne(v0[1]);
  o[2] = f2bf_rne(v0[2]); o[3] = f2bf_rne(v0[3]);
  o[4] = f2bf_rne(v1[0]); o[5] = f2bf_rne(v1[1]);
  o[6] = f2bf_rne(v1[2]); o[7] = f2bf_rne(v1[3]);
  *(u16x8*)(merged + e0) = o;
}

// ---------- kernel 2: W (4096x8192 f32, KxN) -> Wt'' (8192x4096 bf16) -------
// GATE-BLOCK-16 layout: Wt'' row n'' = (j>>4)*64 + gate*16 + (j&15) holds
// W[:, gate*2048 + j]. A GEMM wave's ni=0..3 fragments then carry the four
// gates of the SAME 16 j's -> shuffle-free fused epilogue (tile-size-agnostic).
// LDS: 64x64 f32 tile, XOR-swizzle byte ^= ((k>>3)&7)<<4 on BOTH phases.
__global__ __launch_bounds__(256) void k_transpose_w(
    const float* __restrict__ W, unsigned short* __restrict__ Wt) {
  __shared__ float lt[64 * 64];
  char* lbase = (char*)lt;
  const int t   = threadIdx.x;
  const int g   = blockIdx.x & 3;
  const int jb  = blockIdx.x >> 2;            // 0..31
  const int n0s = g * 2048 + jb * 64;         // source col base in W
  const int k0  = blockIdx.y * 64;            // 4096/64 = 64
#pragma unroll
  for (int i = 0; i < 4; ++i) {
    int kk = (t >> 4) + i * 16;               // 0..63
    int nn = (t & 15) * 4;                    // 0..60 (source-col offset)
    f32x4 v = *(const f32x4*)&W[(size_t)(k0 + kk) * N_ + n0s + nn];
    int by = (kk * 256 + nn * 4) ^ (((kk >> 3) & 7) << 4);
    *(f32x4*)(lbase + by) = v;
  }
  __syncthreads();
#pragma unroll
  for (int i = 0; i < 2; ++i) {
    int jl = (t >> 3) + i * 32;               // 0..63 (j within tile)
    int kc = (t & 7) * 8;                     // 0..56, k>>3 == t&7 for all jj
    u16x8 o;
#pragma unroll
    for (int jj = 0; jj < 8; ++jj) {
      int k  = kc + jj;
      int by = (k * 256 + jl * 4) ^ (((k >> 3) & 7) << 4);
      o[jj] = f2bf_rne(*(const float*)(lbase + by));
    }
    int j    = jb * 64 + jl;                  // j within this gate (0..2047)
    int nrow = ((j >> 4) * 64) + g * 16 + (j & 15);
    *(u16x8*)&Wt[(size_t)nrow * K_ + k0 + kc] = o;
  }
}

// ---------- kernel 3: fused GEMM + LSTM gates, deep-pipelined ---------------
// BM=128, BN=256, BK=64. Grid 32x8 = 256 blocks = 1/CU. 512 thr = 8 waves as
// 2(M) x 4(N); per-wave 64x64, acc[4][4]. 3 LDS buffers (144 KB), 2-deep
// prefetch, counted s_waitcnt vmcnt(6) + raw s_barrier (loads stay in flight
// across barriers - T3/T4). T2 both-sides XOR swizzle ((row&7)<<4) via
// pre-swizzled global staging source + swizzled ds_read col. T5 setprio.
#define NT 64          /* K_/64 K-steps */
#define ABUF 16384     /* 128 rows x 128 B  */
#define BBUF 32768     /* 256 rows x 128 B  */
#define BUFSZ (ABUF + BBUF)

__global__ __launch_bounds__(512, 2) void k_gemm(
    const unsigned short* __restrict__ A,   // 1024 x 4096 bf16 row-major
    const unsigned short* __restrict__ Bt,  // 8192 x 4096 bf16 (gate-16)
    const float* __restrict__ c,            // B x H f32
    float* __restrict__ out) {              // B x H f32 (h_new)
  __shared__ char smem[3 * BUFSZ];          // 144 KB
  char* LA0 = smem;               char* LB0 = smem + ABUF;
  char* LA1 = smem + BUFSZ;       char* LB1 = smem + BUFSZ + ABUF;
  char* LA2 = smem + 2 * BUFSZ;   char* LB2 = smem + 2 * BUFSZ + ABUF;

  const int t    = threadIdx.x;             // 0..511
  const int bx   = blockIdx.x;              // N tile: 0..31 (256 cols)
  const int by   = blockIdx.y;              // M tile: 0..7  (128 rows)
  const int w    = t >> 6;                  // wave 0..7
  const int lane = t & 63;
  const int wr   = w >> 2, wc = w & 3;      // 2(M) x 4(N)
  const int ln15 = lane & 15, kq = (lane >> 4) & 3;

  // ---- staging geometry: lane t covers (row = t>>3 [+64*i], 16B chunk t&7).
  // Global source col pre-XORed by ((row&7)<<4); LDS dest linear (t*16).
  const int srow = t >> 3;                  // 0..63
  const int scb  = (t & 7) * 16;
  const int ssw  = ((srow & 7) << 4);       // sweep +64 keeps row&7
  const int scbx = scb ^ ssw;
  const char* sA0 = (const char*)A  + ((size_t)(by * 128 + srow)      * K_) * 2 + scbx;
  const char* sA1 = (const char*)A  + ((size_t)(by * 128 + srow + 64) * K_) * 2 + scbx;
  const char* sB0 = (const char*)Bt + ((size_t)(bx * 256 + srow)       * K_) * 2 + scbx;
  const char* sB1 = (const char*)Bt + ((size_t)(bx * 256 + srow + 64)  * K_) * 2 + scbx;
  const char* sB2 = (const char*)Bt + ((size_t)(bx * 256 + srow + 128) * K_) * 2 + scbx;
  const char* sB3 = (const char*)Bt + ((size_t)(bx * 256 + srow + 192) * K_) * 2 + scbx;
  const int ldst = t * 16;

#define STAGE(LA, LB, KO) do {                         \
    gl_lds16(sA0 + (KO), (LA) + ldst);                 \
    gl_lds16(sA1 + (KO), (LA) + 8192 + ldst);          \
    gl_lds16(sB0 + (KO), (LB) + ldst);                 \
    gl_lds16(sB1 + (KO), (LB) + 8192 + ldst);          \
    gl_lds16(sB2 + (KO), (LB) + 16384 + ldst);         \
    gl_lds16(sB3 + (KO), (LB) + 24576 + ldst);         \
  } while (0)

  // ---- ds_read geometry: row = band + mi*16 + ln15, colbyte = (ks*64+kq*16)
  // XOR ((row&7)<<4) = XOR ((ln15&7)<<4)  -> 2-way banks (free).
  const int swz  = (ln15 & 7) << 4;
  const int aRow = wr * 8192 + ln15 * 128;  // wr*64 rows * 128 B
  const int bRow = wc * 8192 + ln15 * 128;

  f32x4 acc[4][4] = {};

#define COMPUTE(LA, LB) do {                                             \
    _Pragma("unroll")                                                    \
    for (int ks = 0; ks < 2; ++ks) {                                     \
      const int cb = (ks * 64 + kq * 16) ^ swz;                          \
      bf16x8 a0 = *(const bf16x8*)((LA) + aRow          + cb);           \
      bf16x8 a1 = *(const bf16x8*)((LA) + aRow + 2048   + cb);           \
      bf16x8 a2 = *(const bf16x8*)((LA) + aRow + 4096   + cb);           \
      bf16x8 a3 = *(const bf16x8*)((LA) + aRow + 6144   + cb);           \
      bf16x8 b0 = *(const bf16x8*)((LB) + bRow          + cb);           \
      bf16x8 b1 = *(const bf16x8*)((LB) + bRow + 2048   + cb);           \
      bf16x8 b2 = *(const bf16x8*)((LB) + bRow + 4096   + cb);           \
      bf16x8 b3 = *(const bf16x8*)((LB) + bRow + 6144   + cb);           \
      __builtin_amdgcn_s_setprio(1);                                     \
      acc[0][0] = __builtin_amdgcn_mfma_f32_16x16x32_bf16(a0, b0, acc[0][0], 0, 0, 0); \
      acc[0][1] = __builtin_amdgcn_mfma_f32_16x16x32_bf16(a0, b1, acc[0][1], 0, 0, 0); \
      acc[0][2] = __builtin_amdgcn_mfma_f32_16x16x32_bf16(a0, b2, acc[0][2], 0, 0, 0); \
      acc[0][3] = __builtin_amdgcn_mfma_f32_16x16x32_bf16(a0, b3, acc[0][3], 0, 0, 0); \
      acc[1][0] = __builtin_amdgcn_mfma_f32_16x16x32_bf16(a1, b0, acc[1][0], 0, 0, 0); \
      acc[1][1] = __builtin_amdgcn_mfma_f32_16x16x32_bf16(a1, b1, acc[1][1], 0, 0, 0); \
      acc[1][2] = __builtin_amdgcn_mfma_f32_16x16x32_bf16(a1, b2, acc[1][2], 0, 0, 0); \
      acc[1][3] = __builtin_amdgcn_mfma_f32_16x16x32_bf16(a1, b3, acc[1][3], 0, 0, 0); \
      acc[2][0] = __builtin_amdgcn_mfma_f32_16x16x32_bf16(a2, b0, acc[2][0], 0, 0, 0); \
      acc[2][1] = __builtin_amdgcn_mfma_f32_16x16x32_bf16(a2, b1, acc[2][1], 0, 0, 0); \
      acc[2][2] = __builtin_amdgcn_mfma_f32_16x16x32_bf16(a2, b2, acc[2][2], 0, 0, 0); \
      acc[2][3] = __builtin_amdgcn_mfma_f32_16x16x32_bf16(a2, b3, acc[2][3], 0, 0, 0); \
      acc[3][0] = __builtin_amdgcn_mfma_f32_16x16x32_bf16(a3, b0, acc[3][0], 0, 0, 0); \
      acc[3][1] = __builtin_amdgcn_mfma_f32_16x16x32_bf16(a3, b1, acc[3][1], 0, 0, 0); \
      acc[3][2] = __builtin_amdgcn_mfma_f32_16x16x32_bf16(a3, b2, acc[3][2], 0, 0, 0); \
      acc[3][3] = __builtin_amdgcn_mfma_f32_16x16x32_bf16(a3, b3, acc[3][3], 0, 0, 0); \
      __builtin_amdgcn_s_setprio(0);                                     \
    }                                                                    \
  } while (0)

#define WAITBAR(NSTR) do {                                   \
    asm volatile("s_waitcnt vmcnt(" NSTR ")" ::: "memory");  \
    __builtin_amdgcn_sched_barrier(0);                       \
    __builtin_amdgcn_s_barrier();                            \
    __builtin_amdgcn_sched_barrier(0);                       \
  } while (0)

  // prologue: stage kt=0 -> buf0, kt=1 -> buf1 (12 loads in flight)
  STAGE(LA0, LB0, 0);
  STAGE(LA1, LB1, 128);

  for (int ktb = 0; ktb < 63; ktb += 3) {
    const size_t ko = (size_t)(ktb + 2) * 128;
    // kt = ktb: read buf0, stage kt+2 -> buf2
    WAITBAR("6");
    STAGE(LA2, LB2, ko);
    COMPUTE(LA0, LB0);
    // kt = ktb+1: read buf1, stage kt+3 -> buf0
    WAITBAR("6");
    STAGE(LA0, LB0, ko + 128);
    COMPUTE(LA1, LB1);
    // kt = ktb+2: read buf2, stage kt+4 -> buf1 (skip at ktb=60: kt+4=64)
    WAITBAR("6");
    if (ktb < 60) STAGE(LA1, LB1, ko + 256);
    COMPUTE(LA2, LB2);
  }
  // kt = 63: buf0 (staged at ktb=60 pos1) - full drain, no further stages
  WAITBAR("0");
  COMPUTE(LA0, LB0);

#undef STAGE
#undef COMPUTE
#undef WAITBAR

  // fused epilogue, shuffle-free: C/D col = lane&15, row = kq*4 + reg.
  // Wave's ni = gate; j = (bx*4 + wc)*16 + ln15.
  const int row0 = by * 128 + wr * 64 + kq * 4;
  const int j    = (bx * 4 + wc) * 16 + ln15;
#pragma unroll
  for (int mi = 0; mi < 4; ++mi)
#pragma unroll
    for (int r = 0; r < 4; ++r) {
      int row   = row0 + mi * 16 + r;
      float fg  = acc[mi][0][r];
      float ig  = acc[mi][1][r];
      float gg  = acc[mi][2][r];
      float og  = acc[mi][3][r];
      float cv  = c[(size_t)row * H_ + j];
      float cn  = cv * sigf(fg) + sigf(ig) * tanhf_(gg);
      out[(size_t)row * H_ + j] = sigf(og) * tanhf_(cn);
    }
}

// ---------- launch ----------
extern "C" void kernel_launch(void* const* d_in, const int* in_sizes, int n_in,
                              void* d_out, int out_size, void* d_ws, size_t ws_size,
                              hipStream_t stream) {
  (void)in_sizes; (void)n_in; (void)out_size; (void)ws_size;
  const float* x = (const float*)d_in[0];
  const float* h = (const float*)d_in[1];
  const float* c = (const float*)d_in[2];
  const float* W = (const float*)d_in[3];
  float* out = (float*)d_out;

  char* ws = (char*)d_ws;
  unsigned short* merged = (unsigned short*)ws;                              // 8 MB
  unsigned short* Wt     = (unsigned short*)(ws + (size_t)8  * 1024 * 1024); // 64 MB

  k_convert_merged<<<2048, 256, 0, stream>>>(x, h, merged);
  k_transpose_w<<<dim3(128, 64), 256, 0, stream>>>(W, Wt);
  k_gemm<<<dim3(32, 8), 512, 0, stream>>>(merged, Wt, c, out);
}

// Round 7
// 281.799 us; speedup vs baseline: 1.2170x; 1.0068x over previous
//
#include <hip/hip_runtime.h>

typedef __attribute__((ext_vector_type(4))) float          f32x4;
typedef __attribute__((ext_vector_type(8))) __bf16         bf16x8;
typedef __attribute__((ext_vector_type(8))) unsigned short u16x8;

#define B_  1024
#define D_  2048
#define H_  2048
#define K_  4096   /* D + H  */
#define N_  8192   /* 4 * H  */

// ---------- helpers ----------
__device__ __forceinline__ unsigned short f2bf_rne(float f) {
  unsigned u = __builtin_bit_cast(unsigned, f);
  u += 0x7fffu + ((u >> 16) & 1u);           // round-to-nearest-even
  return (unsigned short)(u >> 16);
}

__device__ __forceinline__ float sigf(float x) {
  return 1.f / (1.f + __expf(-x));
}
__device__ __forceinline__ float tanhf_(float x) {
  float ax = fabsf(x);
  float t  = __expf(-2.f * ax);              // in (0,1], no overflow
  float r  = (1.f - t) / (1.f + t);
  return (x < 0.f) ? -r : r;
}

typedef const __attribute__((address_space(1))) unsigned int* gptr_t;
typedef __attribute__((address_space(3))) unsigned int*       lptr_t;
__device__ __forceinline__ void gl_lds16(const void* g, void* l) {
  __builtin_amdgcn_global_load_lds((gptr_t)g, (lptr_t)l, 16, 0, 0);
}

// ---------- kernel 1: convert [x | h] -> bf16 merged (1024 x 4096) ----------
__global__ __launch_bounds__(256) void k_convert_merged(
    const float* __restrict__ x, const float* __restrict__ h,
    unsigned short* __restrict__ merged) {
  int tid = blockIdx.x * 256 + threadIdx.x;   // 0 .. 524287
  int e0  = tid * 8;                          // element offset in merged
  int b   = e0 >> 12;                         // / 4096
  int col = e0 & 4095;
  const float* src = (col < D_) ? (x + (size_t)b * D_ + col)
                                : (h + (size_t)b * H_ + (col - D_));
  f32x4 v0 = *(const f32x4*)src;
  f32x4 v1 = *(const f32x4*)(src + 4);
  u16x8 o;
  o[0] = f2bf_rne(v0[0]); o[1] = f2bf_rne(v0[1]);
  o[2] = f2bf_rne(v0[2]); o[3] = f2bf_rne(v0[3]);
  o[4] = f2bf_rne(v1[0]); o[5] = f2bf_rne(v1[1]);
  o[6] = f2bf_rne(v1[2]); o[7] = f2bf_rne(v1[3]);
  *(u16x8*)(merged + e0) = o;
}

// ---------- kernel 2: W (4096x8192 f32, KxN) -> Wt'' (8192x4096 bf16) -------
// GATE-BLOCK-16 layout: Wt'' row n'' = (j>>4)*64 + gate*16 + (j&15) holds
// W[:, gate*2048 + j]. A GEMM wave's ni=0..3 fragments then carry the four
// gates of the SAME 16 j's -> shuffle-free fused epilogue.
// LDS: 64x64 f32 tile, XOR-swizzle byte ^= ((k>>3)&7)<<4 on BOTH phases.
__global__ __launch_bounds__(256) void k_transpose_w(
    const float* __restrict__ W, unsigned short* __restrict__ Wt) {
  __shared__ float lt[64 * 64];
  char* lbase = (char*)lt;
  const int t   = threadIdx.x;
  const int g   = blockIdx.x & 3;
  const int jb  = blockIdx.x >> 2;            // 0..31
  const int n0s = g * 2048 + jb * 64;         // source col base in W
  const int k0  = blockIdx.y * 64;            // 4096/64 = 64
#pragma unroll
  for (int i = 0; i < 4; ++i) {
    int kk = (t >> 4) + i * 16;               // 0..63
    int nn = (t & 15) * 4;                    // 0..60 (source-col offset)
    f32x4 v = *(const f32x4*)&W[(size_t)(k0 + kk) * N_ + n0s + nn];
    int by = (kk * 256 + nn * 4) ^ (((kk >> 3) & 7) << 4);
    *(f32x4*)(lbase + by) = v;
  }
  __syncthreads();
#pragma unroll
  for (int i = 0; i < 2; ++i) {
    int jl = (t >> 3) + i * 32;               // 0..63 (j within tile)
    int kc = (t & 7) * 8;                     // 0..56, k>>3 == t&7 for all jj
    u16x8 o;
#pragma unroll
    for (int jj = 0; jj < 8; ++jj) {
      int k  = kc + jj;
      int by = (k * 256 + jl * 4) ^ (((k >> 3) & 7) << 4);
      o[jj] = f2bf_rne(*(const float*)(lbase + by));
    }
    int j    = jb * 64 + jl;                  // j within this gate (0..2047)
    int nrow = ((j >> 4) * 64) + g * 16 + (j & 15);
    *(u16x8*)&Wt[(size_t)nrow * K_ + k0 + kc] = o;
  }
}

// ---------- kernel 3: fused GEMM + LSTM gates, deep-pipelined ---------------
// BM=128, BN=256, BK=64. Grid 32x8 = 256 blocks = 1/CU. 512 thr = 8 waves as
// 2(M) x 4(N); per-wave 64x64, acc[4][4]. 3 LDS buffers (144 KB), 2-deep
// prefetch, counted vmcnt(6) + raw s_barrier (T3/T4). T2 both-sides swizzle.
// ROUND 7: all 16 ds_reads (both ks halves) issue BEFORE the MFMA cluster so
// ks=1's reads complete under ks=0's MFMAs (compiler emits counted lgkmcnt).
#define ABUF 16384     /* 128 rows x 128 B  */
#define BBUF 32768     /* 256 rows x 128 B  */
#define BUFSZ (ABUF + BBUF)

__global__ __launch_bounds__(512, 2) void k_gemm(
    const unsigned short* __restrict__ A,   // 1024 x 4096 bf16 row-major
    const unsigned short* __restrict__ Bt,  // 8192 x 4096 bf16 (gate-16)
    const float* __restrict__ c,            // B x H f32
    float* __restrict__ out) {              // B x H f32 (h_new)
  __shared__ char smem[3 * BUFSZ];          // 144 KB
  char* LA0 = smem;               char* LB0 = smem + ABUF;
  char* LA1 = smem + BUFSZ;       char* LB1 = smem + BUFSZ + ABUF;
  char* LA2 = smem + 2 * BUFSZ;   char* LB2 = smem + 2 * BUFSZ + ABUF;

  const int t    = threadIdx.x;             // 0..511
  const int bx   = blockIdx.x;              // N tile: 0..31 (256 cols)
  const int by   = blockIdx.y;              // M tile: 0..7  (128 rows)
  const int w    = t >> 6;                  // wave 0..7
  const int lane = t & 63;
  const int wr   = w >> 2, wc = w & 3;      // 2(M) x 4(N)
  const int ln15 = lane & 15, kq = (lane >> 4) & 3;

  // staging: lane t covers (row = t>>3 [+64*i], 16B chunk t&7); global source
  // col pre-XORed by ((row&7)<<4); LDS dest linear (t*16).  (rule #21)
  const int srow = t >> 3;                  // 0..63
  const int scb  = (t & 7) * 16;
  const int scbx = scb ^ ((srow & 7) << 4);
  const char* sA0 = (const char*)A  + ((size_t)(by * 128 + srow)       * K_) * 2 + scbx;
  const char* sA1 = (const char*)A  + ((size_t)(by * 128 + srow + 64)  * K_) * 2 + scbx;
  const char* sB0 = (const char*)Bt + ((size_t)(bx * 256 + srow)       * K_) * 2 + scbx;
  const char* sB1 = (const char*)Bt + ((size_t)(bx * 256 + srow + 64)  * K_) * 2 + scbx;
  const char* sB2 = (const char*)Bt + ((size_t)(bx * 256 + srow + 128) * K_) * 2 + scbx;
  const char* sB3 = (const char*)Bt + ((size_t)(bx * 256 + srow + 192) * K_) * 2 + scbx;
  const int ldst = t * 16;

#define STAGE(LA, LB, KO) do {                         \
    gl_lds16(sA0 + (KO), (LA) + ldst);                 \
    gl_lds16(sA1 + (KO), (LA) + 8192 + ldst);          \
    gl_lds16(sB0 + (KO), (LB) + ldst);                 \
    gl_lds16(sB1 + (KO), (LB) + 8192 + ldst);          \
    gl_lds16(sB2 + (KO), (LB) + 16384 + ldst);         \
    gl_lds16(sB3 + (KO), (LB) + 24576 + ldst);         \
  } while (0)

  // ds_read: row = band + mi*16 + ln15, colbyte = (ks*64+kq*16) ^ ((ln15&7)<<4)
  const int swz  = (ln15 & 7) << 4;
  const int cb0  = (kq * 16) ^ swz;
  const int cb1  = cb0 ^ 64;                // ks=1 (bit 6 flips through XOR)
  const int aRow = wr * 8192 + ln15 * 128;
  const int bRow = wc * 8192 + ln15 * 128;

  f32x4 acc[4][4] = {};

  // all 16 reads issue first (ks0 then ks1), THEN 32 MFMAs: compiler inserts
  // lgkmcnt(8) before the first MFMA -> ks1 reads overlap ks0 MFMAs.
#define KSTEP(LA, LB) do {                                               \
    bf16x8 a0 = *(const bf16x8*)((LA) + aRow        + cb0);              \
    bf16x8 a1 = *(const bf16x8*)((LA) + aRow + 2048 + cb0);              \
    bf16x8 a2 = *(const bf16x8*)((LA) + aRow + 4096 + cb0);              \
    bf16x8 a3 = *(const bf16x8*)((LA) + aRow + 6144 + cb0);              \
    bf16x8 b0 = *(const bf16x8*)((LB) + bRow        + cb0);              \
    bf16x8 b1 = *(const bf16x8*)((LB) + bRow + 2048 + cb0);              \
    bf16x8 b2 = *(const bf16x8*)((LB) + bRow + 4096 + cb0);              \
    bf16x8 b3 = *(const bf16x8*)((LB) + bRow + 6144 + cb0);              \
    bf16x8 e0 = *(const bf16x8*)((LA) + aRow        + cb1);              \
    bf16x8 e1 = *(const bf16x8*)((LA) + aRow + 2048 + cb1);              \
    bf16x8 e2 = *(const bf16x8*)((LA) + aRow + 4096 + cb1);              \
    bf16x8 e3 = *(const bf16x8*)((LA) + aRow + 6144 + cb1);              \
    bf16x8 f0 = *(const bf16x8*)((LB) + bRow        + cb1);              \
    bf16x8 f1 = *(const bf16x8*)((LB) + bRow + 2048 + cb1);              \
    bf16x8 f2 = *(const bf16x8*)((LB) + bRow + 4096 + cb1);              \
    bf16x8 f3 = *(const bf16x8*)((LB) + bRow + 6144 + cb1);              \
    __builtin_amdgcn_s_setprio(1);                                       \
    acc[0][0] = __builtin_amdgcn_mfma_f32_16x16x32_bf16(a0, b0, acc[0][0], 0, 0, 0); \
    acc[0][1] = __builtin_amdgcn_mfma_f32_16x16x32_bf16(a0, b1, acc[0][1], 0, 0, 0); \
    acc[0][2] = __builtin_amdgcn_mfma_f32_16x16x32_bf16(a0, b2, acc[0][2], 0, 0, 0); \
    acc[0][3] = __builtin_amdgcn_mfma_f32_16x16x32_bf16(a0, b3, acc[0][3], 0, 0, 0); \
    acc[1][0] = __builtin_amdgcn_mfma_f32_16x16x32_bf16(a1, b0, acc[1][0], 0, 0, 0); \
    acc[1][1] = __builtin_amdgcn_mfma_f32_16x16x32_bf16(a1, b1, acc[1][1], 0, 0, 0); \
    acc[1][2] = __builtin_amdgcn_mfma_f32_16x16x32_bf16(a1, b2, acc[1][2], 0, 0, 0); \
    acc[1][3] = __builtin_amdgcn_mfma_f32_16x16x32_bf16(a1, b3, acc[1][3], 0, 0, 0); \
    acc[2][0] = __builtin_amdgcn_mfma_f32_16x16x32_bf16(a2, b0, acc[2][0], 0, 0, 0); \
    acc[2][1] = __builtin_amdgcn_mfma_f32_16x16x32_bf16(a2, b1, acc[2][1], 0, 0, 0); \
    acc[2][2] = __builtin_amdgcn_mfma_f32_16x16x32_bf16(a2, b2, acc[2][2], 0, 0, 0); \
    acc[2][3] = __builtin_amdgcn_mfma_f32_16x16x32_bf16(a2, b3, acc[2][3], 0, 0, 0); \
    acc[3][0] = __builtin_amdgcn_mfma_f32_16x16x32_bf16(a3, b0, acc[3][0], 0, 0, 0); \
    acc[3][1] = __builtin_amdgcn_mfma_f32_16x16x32_bf16(a3, b1, acc[3][1], 0, 0, 0); \
    acc[3][2] = __builtin_amdgcn_mfma_f32_16x16x32_bf16(a3, b2, acc[3][2], 0, 0, 0); \
    acc[3][3] = __builtin_amdgcn_mfma_f32_16x16x32_bf16(a3, b3, acc[3][3], 0, 0, 0); \
    acc[0][0] = __builtin_amdgcn_mfma_f32_16x16x32_bf16(e0, f0, acc[0][0], 0, 0, 0); \
    acc[0][1] = __builtin_amdgcn_mfma_f32_16x16x32_bf16(e0, f1, acc[0][1], 0, 0, 0); \
    acc[0][2] = __builtin_amdgcn_mfma_f32_16x16x32_bf16(e0, f2, acc[0][2], 0, 0, 0); \
    acc[0][3] = __builtin_amdgcn_mfma_f32_16x16x32_bf16(e0, f3, acc[0][3], 0, 0, 0); \
    acc[1][0] = __builtin_amdgcn_mfma_f32_16x16x32_bf16(e1, f0, acc[1][0], 0, 0, 0); \
    acc[1][1] = __builtin_amdgcn_mfma_f32_16x16x32_bf16(e1, f1, acc[1][1], 0, 0, 0); \
    acc[1][2] = __builtin_amdgcn_mfma_f32_16x16x32_bf16(e1, f2, acc[1][2], 0, 0, 0); \
    acc[1][3] = __builtin_amdgcn_mfma_f32_16x16x32_bf16(e1, f3, acc[1][3], 0, 0, 0); \
    acc[2][0] = __builtin_amdgcn_mfma_f32_16x16x32_bf16(e2, f0, acc[2][0], 0, 0, 0); \
    acc[2][1] = __builtin_amdgcn_mfma_f32_16x16x32_bf16(e2, f1, acc[2][1], 0, 0, 0); \
    acc[2][2] = __builtin_amdgcn_mfma_f32_16x16x32_bf16(e2, f2, acc[2][2], 0, 0, 0); \
    acc[2][3] = __builtin_amdgcn_mfma_f32_16x16x32_bf16(e2, f3, acc[2][3], 0, 0, 0); \
    acc[3][0] = __builtin_amdgcn_mfma_f32_16x16x32_bf16(e3, f0, acc[3][0], 0, 0, 0); \
    acc[3][1] = __builtin_amdgcn_mfma_f32_16x16x32_bf16(e3, f1, acc[3][1], 0, 0, 0); \
    acc[3][2] = __builtin_amdgcn_mfma_f32_16x16x32_bf16(e3, f2, acc[3][2], 0, 0, 0); \
    acc[3][3] = __builtin_amdgcn_mfma_f32_16x16x32_bf16(e3, f3, acc[3][3], 0, 0, 0); \
    __builtin_amdgcn_s_setprio(0);                                       \
  } while (0)

#define WAITBAR(NSTR) do {                                   \
    asm volatile("s_waitcnt vmcnt(" NSTR ")" ::: "memory");  \
    __builtin_amdgcn_sched_barrier(0);                       \
    __builtin_amdgcn_s_barrier();                            \
    __builtin_amdgcn_sched_barrier(0);                       \
  } while (0)

  // prologue: stage kt=0 -> buf0, kt=1 -> buf1 (12 loads in flight)
  STAGE(LA0, LB0, 0);
  STAGE(LA1, LB1, 128);

  for (int ktb = 0; ktb < 63; ktb += 3) {
    const size_t ko = (size_t)(ktb + 2) * 128;
    WAITBAR("6");
    STAGE(LA2, LB2, ko);
    KSTEP(LA0, LB0);
    WAITBAR("6");
    STAGE(LA0, LB0, ko + 128);
    KSTEP(LA1, LB1);
    WAITBAR("6");
    if (ktb < 60) STAGE(LA1, LB1, ko + 256);
    KSTEP(LA2, LB2);
  }
  WAITBAR("0");
  KSTEP(LA0, LB0);

#undef STAGE
#undef KSTEP
#undef WAITBAR

  // fused epilogue, shuffle-free: C/D col = lane&15, row = kq*4 + reg.
  // Wave's ni = gate; j = (bx*4 + wc)*16 + ln15.
  const int row0 = by * 128 + wr * 64 + kq * 4;
  const int j    = (bx * 4 + wc) * 16 + ln15;
#pragma unroll
  for (int mi = 0; mi < 4; ++mi)
#pragma unroll
    for (int r = 0; r < 4; ++r) {
      int row   = row0 + mi * 16 + r;
      float fg  = acc[mi][0][r];
      float ig  = acc[mi][1][r];
      float gg  = acc[mi][2][r];
      float og  = acc[mi][3][r];
      float cv  = c[(size_t)row * H_ + j];
      float cn  = cv * sigf(fg) + sigf(ig) * tanhf_(gg);
      out[(size_t)row * H_ + j] = sigf(og) * tanhf_(cn);
    }
}

// ---------- launch ----------
extern "C" void kernel_launch(void* const* d_in, const int* in_sizes, int n_in,
                              void* d_out, int out_size, void* d_ws, size_t ws_size,
                              hipStream_t stream) {
  (void)in_sizes; (void)n_in; (void)out_size; (void)ws_size;
  const float* x = (const float*)d_in[0];
  const float* h = (const float*)d_in[1];
  const float* c = (const float*)d_in[2];
  const float* W = (const float*)d_in[3];
  float* out = (float*)d_out;

  char* ws = (char*)d_ws;
  unsigned short* merged = (unsigned short*)ws;                              // 8 MB
  unsigned short* Wt     = (unsigned short*)(ws + (size_t)8  * 1024 * 1024); // 64 MB

  k_convert_merged<<<2048, 256, 0, stream>>>(x, h, merged);
  k_transpose_w<<<dim3(128, 64), 256, 0, stream>>>(W, Wt);
  k_gemm<<<dim3(32, 8), 512, 0, stream>>>(merged, Wt, c, out);
}